// Round 13
// baseline (48.097 us; speedup 1.0000x reference)
//
#include <hip/hip_runtime.h>
#include <hip/hip_bf16.h>

#define NKVH 4
#define SEQ 4096
#define BLK 64
#define NW 8
#define NQB 64

typedef __attribute__((ext_vector_type(8))) short bf16x8;
typedef __attribute__((ext_vector_type(4))) float f32x4;

// round-half-up f32->bf16 pair pack: [bf16(hi)<<16 | bf16(lo)] (validated r1-r12)
__device__ __forceinline__ unsigned pkbf(unsigned lo, unsigned hi) {
  return __builtin_amdgcn_perm(hi + 0x8000u, lo + 0x8000u, 0x07060302u);
}

__device__ __forceinline__ void gload16(const void* g, void* l) {
  __builtin_amdgcn_global_load_lds(
      (const __attribute__((address_space(1))) void*)g,
      (__attribute__((address_space(3))) void*)l, 16, 0, 0);
}

// ---- pre-pass: K (pi_f-permuted rows) and V^T -> bf16, MFMA-fragment-linear ----
// (unchanged from round 10/12)
__global__ __launch_bounds__(256, 2)
void prep_kernel(const float* __restrict__ kp, const float* __restrict__ vp,
                 short* __restrict__ kw, short* __restrict__ vt)
{
  const int ki = blockIdx.x, kvh = blockIdx.y, b = blockIdx.z;
  const size_t base = (((size_t)(b*NKVH + kvh)*SEQ) + (size_t)ki*BLK)*64;
  __shared__ float sk[64][72];
  __shared__ float sv[64][72];
  const int t = threadIdx.x;
  #pragma unroll
  for (int it = 0; it < 4; ++it) {
    const int i = t + it*256;
    const int row = i >> 4, c4 = i & 15;
    float4 a = *(const float4*)(kp + base + row*64 + c4*4);
    *(float4*)&sk[row][c4*4] = a;
    float4 v = *(const float4*)(vp + base + row*64 + c4*4);
    *(float4*)&sv[row][c4*4] = v;
  }
  __syncthreads();
  #pragma unroll
  for (int it = 0; it < 2; ++it) {
    const int o = t + it*256;
    const int s = o >> 8, fd = (o >> 6) & 3, lg = (o >> 4) & 3, lr = o & 15;
    const int krow = 8*(lr >> 2) + (lr & 3) + 4*(fd & 1) + 32*(fd >> 1);
    const float* src = &sk[krow][s*32 + lg*8];
    uint4 w;
    w.x = pkbf(__float_as_uint(src[0]), __float_as_uint(src[1]));
    w.y = pkbf(__float_as_uint(src[2]), __float_as_uint(src[3]));
    w.z = pkbf(__float_as_uint(src[4]), __float_as_uint(src[5]));
    w.w = pkbf(__float_as_uint(src[6]), __float_as_uint(src[7]));
    *(uint4*)(kw + base + (size_t)o*8) = w;
    const int d = fd*16 + lr;
    const int n0 = s*32 + lg*8;
    uint4 u;
    u.x = pkbf(__float_as_uint(sv[n0+0][d]), __float_as_uint(sv[n0+1][d]));
    u.y = pkbf(__float_as_uint(sv[n0+2][d]), __float_as_uint(sv[n0+3][d]));
    u.z = pkbf(__float_as_uint(sv[n0+4][d]), __float_as_uint(sv[n0+5][d]));
    u.w = pkbf(__float_as_uint(sv[n0+6][d]), __float_as_uint(sv[n0+7][d]));
    *(uint4*)(vt + base + (size_t)o*8) = u;
  }
}

// ---- main: cross-window pipeline — QK(wi) || PV(wi-1) || sm(wi) per iteration.
//      2 row-groups/wave, P-in-regs, no-max softmax, ones-MFMA row sums. ----
__global__ __launch_bounds__(256, 2)
void sattn_kernel(const float* __restrict__ qp, const short* __restrict__ kw,
                  const short* __restrict__ vt, const float* __restrict__ alibi,
                  const int* __restrict__ seg, const int* __restrict__ bidx,
                  float* __restrict__ outp)
{
  const int raw = blockIdx.x;
  const int xcd = raw & 7, li = raw >> 3;
  const int b = xcd >> 2, kvh = xcd & 3;
  const int qb = li & 63, hp = li >> 6;

  const int tid = threadIdx.x;
  const int wave = tid >> 6, lane = tid & 63;
  const int lr = lane & 15, lg = lane >> 4;
  const int wh = wave & 1, wq = wave >> 1;   // head-in-pair, row-half
  const int head = kvh*4 + hp*2 + wh;

  __shared__ short klds[2][4096];   // K: 2 buffers
  __shared__ short vlds[3][4096];   // V: 3 buffers (PV runs one window behind)

  int kis[NW];
  #pragma unroll
  for (int i = 0; i < NW; ++i) kis[i] = bidx[qb*NW + i];

  int m_glob[2], mloc[2], sq[2];
  #pragma unroll
  for (int g = 0; g < 2; ++g) {
    mloc[g] = (wq*2 + g)*16 + lr;
    m_glob[g] = qb*BLK + mloc[g];
    sq[g] = seg[b*SEQ + m_glob[g]];
  }
  const float LOG2E = 1.4426950408889634f;
  const float nslope = -alibi[head] * LOG2E;

  const short* kbase = kw + ((size_t)(b*NKVH + kvh)*SEQ)*64;
  const short* vbase = vt + ((size_t)(b*NKVH + kvh)*SEQ)*64;

  auto STAGE = [&](int kbuf, int vbuf, int wi) {
    const int ki = kis[wi] < 0 ? 0 : kis[wi];
    const char* ksrc = (const char*)(kbase + (size_t)ki*4096);
    const char* vsrc = (const char*)(vbase + (size_t)ki*4096);
    gload16(ksrc + tid*16,        (char*)&klds[kbuf][0] + wave*1024);
    gload16(ksrc + 4096 + tid*16, (char*)&klds[kbuf][0] + 4096 + wave*1024);
    gload16(vsrc + tid*16,        (char*)&vlds[vbuf][0] + wave*1024);
    gload16(vsrc + 4096 + tid*16, (char*)&vlds[vbuf][0] + 4096 + wave*1024);
  };

  STAGE(0, 0, 0);

  // Q (scaled by 0.125*log2e) into registers, bf16, for both row-groups
  bf16x8 qf[2][2];   // [g][s]
  {
    const float qs = 0.125f * LOG2E;
    #pragma unroll
    for (int g = 0; g < 2; ++g) {
      const float* qrow = qp + (((size_t)b*16 + head)*SEQ + m_glob[g])*64;
      #pragma unroll
      for (int s = 0; s < 2; ++s) {
        float4 a = *(const float4*)(qrow + s*32 + lg*8);
        float4 c = *(const float4*)(qrow + s*32 + lg*8 + 4);
        union { unsigned u[4]; bf16x8 v; } cv;
        cv.u[0] = pkbf(__float_as_uint(a.x*qs), __float_as_uint(a.y*qs));
        cv.u[1] = pkbf(__float_as_uint(a.z*qs), __float_as_uint(a.w*qs));
        cv.u[2] = pkbf(__float_as_uint(c.x*qs), __float_as_uint(c.y*qs));
        cv.u[3] = pkbf(__float_as_uint(c.z*qs), __float_as_uint(c.w*qs));
        qf[g][s] = cv.v;
      }
    }
  }

  // all-ones A-fragment for row-sum MFMA
  union { unsigned short us[8]; bf16x8 v; } one_u;
  #pragma unroll
  for (int i = 0; i < 8; ++i) one_u.us[i] = 0x3F80;
  const bf16x8 onesf = one_u.v;

  f32x4 oacc[2][4], osum[2];
  #pragma unroll
  for (int g = 0; g < 2; ++g) {
    f32x4 z = {0.f,0.f,0.f,0.f};
    osum[g] = z;
    #pragma unroll
    for (int dt = 0; dt < 4; ++dt) oacc[g][dt] = z;
  }

  unsigned pkbuf[2][2][4][2];   // [wi&1][g][f][pair] — static-indexed after unroll

  __syncthreads();   // buf0 staged

  #pragma unroll
  for (int wi = 0; wi < NW; ++wi) {
    if (wi + 1 < NW) STAGE((wi+1)&1, (wi+1)%3, wi+1);

    const int kvi = kis[wi];
    const int kcl = kvi < 0 ? 0 : kvi;

    // seg ids for this window (issued early; latency hides under the MFMAs)
    int skr[4][4];
    #pragma unroll
    for (int f = 0; f < 4; ++f) {
      const int nb = lg*8 + 4*(f & 1) + 32*(f >> 1);
      const int4 s4 = *(const int4*)(seg + b*SEQ + kcl*BLK + nb);
      skr[f][0] = s4.x; skr[f][1] = s4.y; skr[f][2] = s4.z; skr[f][3] = s4.w;
    }

    // ---- QK^T(wi): K fragments read once, feed both row-groups ----
    f32x4 sacc[2][4];
    #pragma unroll
    for (int g = 0; g < 2; ++g)
      #pragma unroll
      for (int f = 0; f < 4; ++f) { f32x4 z = {0.f,0.f,0.f,0.f}; sacc[g][f] = z; }
    #pragma unroll
    for (int s = 0; s < 2; ++s) {
      bf16x8 kf[4];
      #pragma unroll
      for (int f = 0; f < 4; ++f)
        kf[f] = *(const bf16x8*)&klds[wi&1][(s*256 + f*64 + lane)*8];
      __builtin_amdgcn_s_setprio(1);
      #pragma unroll
      for (int f = 0; f < 4; ++f)
        sacc[0][f] = __builtin_amdgcn_mfma_f32_16x16x32_bf16(kf[f], qf[0][s], sacc[0][f], 0, 0, 0);
      #pragma unroll
      for (int f = 0; f < 4; ++f)
        sacc[1][f] = __builtin_amdgcn_mfma_f32_16x16x32_bf16(kf[f], qf[1][s], sacc[1][f], 0, 0, 0);
      __builtin_amdgcn_s_setprio(0);
    }

    // ---- PV(wi-1): independent of QK(wi) and of sm(wi) — overlaps both ----
    if (wi > 0) {
      #pragma unroll
      for (int s = 0; s < 2; ++s) {
        bf16x8 vf[4];
        #pragma unroll
        for (int dt = 0; dt < 4; ++dt)
          vf[dt] = *(const bf16x8*)&vlds[(wi-1)%3][(s*256 + dt*64 + lane)*8];
        union { unsigned u[4]; bf16x8 v; } pf0, pf1;
        pf0.u[0] = pkbuf[(wi-1)&1][0][2*s][0]; pf0.u[1] = pkbuf[(wi-1)&1][0][2*s][1];
        pf0.u[2] = pkbuf[(wi-1)&1][0][2*s+1][0]; pf0.u[3] = pkbuf[(wi-1)&1][0][2*s+1][1];
        pf1.u[0] = pkbuf[(wi-1)&1][1][2*s][0]; pf1.u[1] = pkbuf[(wi-1)&1][1][2*s][1];
        pf1.u[2] = pkbuf[(wi-1)&1][1][2*s+1][0]; pf1.u[3] = pkbuf[(wi-1)&1][1][2*s+1][1];
        __builtin_amdgcn_s_setprio(1);
        #pragma unroll
        for (int dt = 0; dt < 4; ++dt)
          oacc[0][dt] = __builtin_amdgcn_mfma_f32_16x16x32_bf16(vf[dt], pf0.v, oacc[0][dt], 0, 0, 0);
        #pragma unroll
        for (int dt = 0; dt < 4; ++dt)
          oacc[1][dt] = __builtin_amdgcn_mfma_f32_16x16x32_bf16(vf[dt], pf1.v, oacc[1][dt], 0, 0, 0);
        osum[0] = __builtin_amdgcn_mfma_f32_16x16x32_bf16(onesf, pf0.v, osum[0], 0, 0, 0);
        osum[1] = __builtin_amdgcn_mfma_f32_16x16x32_bf16(onesf, pf1.v, osum[1], 0, 0, 0);
        __builtin_amdgcn_s_setprio(0);
      }
    }

    // ---- sm(wi): mask + ALiBi + exp + pack (VALU; overlaps MFMA drain) ----
    {
      const bool wdead = (kvi < 0);
      #pragma unroll
      for (int g = 0; g < 2; ++g) {
        const float fdmb = (float)(m_glob[g] - kcl*BLK);
        #pragma unroll
        for (int f = 0; f < 4; ++f) {
          const int nb = lg*8 + 4*(f & 1) + 32*(f >> 1);
          const float fbase = fdmb - (float)nb;
          float p[4];
          #pragma unroll
          for (int r = 0; r < 4; ++r) {
            bool dead = wdead || (skr[f][r] != sq[g]);
            if (wi == NW-1) dead = dead || ((nb + r) > mloc[g]);
            const float pd = dead ? 3.0e34f : (fbase - (float)r);
            p[r] = __builtin_amdgcn_exp2f(fmaf(nslope, pd, sacc[g][f][r]));
          }
          pkbuf[wi&1][g][f][0] = pkbf(__float_as_uint(p[0]), __float_as_uint(p[1]));
          pkbuf[wi&1][g][f][1] = pkbf(__float_as_uint(p[2]), __float_as_uint(p[3]));
        }
      }
    }
    __syncthreads();
  }

  // ---- drain: PV(7) (vlds[7%3=1], pkbuf[1]) ----
  #pragma unroll
  for (int s = 0; s < 2; ++s) {
    bf16x8 vf[4];
    #pragma unroll
    for (int dt = 0; dt < 4; ++dt)
      vf[dt] = *(const bf16x8*)&vlds[1][(s*256 + dt*64 + lane)*8];
    union { unsigned u[4]; bf16x8 v; } pf0, pf1;
    pf0.u[0] = pkbuf[1][0][2*s][0]; pf0.u[1] = pkbuf[1][0][2*s][1];
    pf0.u[2] = pkbuf[1][0][2*s+1][0]; pf0.u[3] = pkbuf[1][0][2*s+1][1];
    pf1.u[0] = pkbuf[1][1][2*s][0]; pf1.u[1] = pkbuf[1][1][2*s][1];
    pf1.u[2] = pkbuf[1][1][2*s+1][0]; pf1.u[3] = pkbuf[1][1][2*s+1][1];
    #pragma unroll
    for (int dt = 0; dt < 4; ++dt)
      oacc[0][dt] = __builtin_amdgcn_mfma_f32_16x16x32_bf16(vf[dt], pf0.v, oacc[0][dt], 0, 0, 0);
    #pragma unroll
    for (int dt = 0; dt < 4; ++dt)
      oacc[1][dt] = __builtin_amdgcn_mfma_f32_16x16x32_bf16(vf[dt], pf1.v, oacc[1][dt], 0, 0, 0);
    osum[0] = __builtin_amdgcn_mfma_f32_16x16x32_bf16(onesf, pf0.v, osum[0], 0, 0, 0);
    osum[1] = __builtin_amdgcn_mfma_f32_16x16x32_bf16(onesf, pf1.v, osum[1], 0, 0, 0);
  }

  // ---- epilogue: osum[g][0] is the full row sum ----
  #pragma unroll
  for (int g = 0; g < 2; ++g) {
    const float lrow = osum[g][0];
    const float inv = lrow > 0.f ? 1.f/lrow : 0.f;
    float* dst = outp + (((size_t)b*16 + head)*SEQ + m_glob[g])*64;
    #pragma unroll
    for (int dt = 0; dt < 4; ++dt) {
      float4 o;
      o.x = oacc[g][dt][0]*inv; o.y = oacc[g][dt][1]*inv;
      o.z = oacc[g][dt][2]*inv; o.w = oacc[g][dt][3]*inv;
      *(float4*)&dst[dt*16 + lg*4] = o;
    }
  }
}

extern "C" void kernel_launch(void* const* d_in, const int* in_sizes, int n_in,
                              void* d_out, int out_size, void* d_ws, size_t ws_size,
                              hipStream_t stream) {
  const float* q    = (const float*)d_in[0];
  const float* k    = (const float*)d_in[1];
  const float* v    = (const float*)d_in[2];
  const float* al   = (const float*)d_in[3];
  const int*   sg   = (const int*)d_in[4];
  const int*   bi   = (const int*)d_in[5];
  short* kws  = (short*)d_ws;                              // 4 MiB
  short* vtws = (short*)((char*)d_ws + (size_t)(1u<<22));  // 4 MiB
  dim3 pgrid(NQB, NKVH, 2);
  prep_kernel<<<pgrid, 256, 0, stream>>>(k, v, kws, vtws);
  sattn_kernel<<<dim3(1024), 256, 0, stream>>>(q, kws, vtws, al, sg, bi, (float*)d_out);
}